// Round 6
// baseline (385.932 us; speedup 1.0000x reference)
//
#include <hip/hip_runtime.h>

// CRF NLL on MI355X, round 8: WAVE-AUTONOMOUS segments — no barriers at all.
// 256 blocks x 64 threads: one wave = one scan segment (bb = bid>>1, dir =
// bid&1; fwd/bwd split per round 7, verified). Lane l owns output cols
// 2l,2l+1 and keeps the full exp(trans) columns in REGISTERS (128 v2f =
// 256 VGPR; 1 wave/SIMD so up to ~450 no-spill). Per step:
//   32x ds_read_b128 broadcast (uniform addr) of the whole 128-float state
//   -> 128 pk-FMA full dot products (NO cross-lane reduce, NO barrier)
//   -> v = exp(feat)*dot (every-4th-step rescale by u[0] = first read's .x)
//   -> ds_write_b64 own 2 cols -> s_waitcnt lgkmcnt(0) (in-wave visibility).
// Read latency hides under the 256cy FMA issue; step ~480cy vs round-7's 864.
// Also: no memset, no atomics (per-batch ws slots), fused join+final epilogue
// -> 2 dispatches total.

#define BB   128
#define TT   512
#define CC   128
#define PF   4
#define WS_STRIDE 320
// ws layout per batch bb at ws + 16 + bb*320:
//   [0:128) aM (fwd final vector)   [128:256) bM (bwd final vector)
//   [256] SF   [257] SB   [258] gold score partial
// total ws bytes: (16 + 128*320)*4 ~= 164 KB

typedef float v2f __attribute__((ext_vector_type(2)));

__device__ __forceinline__ void wait_lds() {
    // In-wave LDS visibility: drain ds ops; "memory" clobber keeps the
    // compiler from moving LDS accesses across it. Does NOT touch vmcnt
    // (global feats prefetch stays in flight).
    asm volatile("s_waitcnt lgkmcnt(0)" ::: "memory");
}

__global__ __launch_bounds__(64, 1) void crf_scan(
    const float* __restrict__ feats,
    const int*   __restrict__ mask,
    const int*   __restrict__ tags,
    const float* __restrict__ trans,
    float*       __restrict__ ws)
{
    const int bid  = blockIdx.x;
    const int bb   = bid >> 1;
    const int dir  = bid & 1;        // 0 = forward scan, 1 = backward scan
    const int lane = threadIdx.x;    // 0..63, one wave
    const int j0   = lane * 2;
    const int j1   = j0 + 1;

    __shared__ __align__(16) float buf[2][CC];   // ping-pong state vector

    const int base = bb * TT;

    // ---- sequence length (contiguous prefix mask) + gold score ----
    int len = 0;
    int mvals[8];
    #pragma unroll
    for (int c2 = 0; c2 < 8; ++c2) {
        mvals[c2] = mask[base + c2 * 64 + lane];
        len += __popcll(__ballot(mvals[c2] != 0));
    }
    if (dir == 0) {                  // gold path scored by the fwd block only
        float sc = 0.0f;
        #pragma unroll
        for (int c2 = 0; c2 < 8; ++c2) {
            const int t = c2 * 64 + lane;
            if (mvals[c2]) {
                const int tg = tags[base + t];
                sc += feats[((size_t)(base + t)) * CC + tg];
                sc += (t == 0) ? trans[(CC - 2) * CC + tg]
                               : trans[tags[base + t - 1] * CC + tg];
                const int nm = (t == TT - 1) ? 0 : mask[base + t + 1];
                if (!nm) sc += trans[tg * CC + (CC - 1)];
            }
        }
        #pragma unroll
        for (int o = 1; o <= 32; o <<= 1) sc += __shfl_xor(sc, o);
        if (lane == 0) ws[16 + (size_t)bb * WS_STRIDE + 258] = sc;
    }

    // ---- E fragments in registers: 128 v2f = 256 VGPR.
    //  fwd: F0[rr]=(E[2rr][j0],E[2rr+1][j0]), F1 same for j1  (column-major)
    //  bwd: F0[rr]=(E[j0][2rr],E[j0][2rr+1]), F1 same for j1  (row-major)
    //  so step dot = sum_rr pk(F[rr] * u[2rr..2rr+1]) in both cases. ----
    v2f F0[64], F1[64];
    if (dir == 0) {
        #pragma unroll
        for (int rr = 0; rr < 64; ++rr) {
            const float2 ta = *(const float2*)&trans[(size_t)(2 * rr    ) * CC + j0];
            const float2 tb = *(const float2*)&trans[(size_t)(2 * rr + 1) * CC + j0];
            v2f e0; e0.x = __expf(ta.x); e0.y = __expf(tb.x); F0[rr] = e0;
            v2f e1; e1.x = __expf(ta.y); e1.y = __expf(tb.y); F1[rr] = e1;
        }
    } else {
        #pragma unroll
        for (int q = 0; q < 32; ++q) {
            const float4 u0 = *(const float4*)&trans[(size_t)j0 * CC + 4 * q];
            const float4 u1 = *(const float4*)&trans[(size_t)j1 * CC + 4 * q];
            v2f e;
            e.x = __expf(u0.x); e.y = __expf(u0.y); F0[2 * q]     = e;
            e.x = __expf(u0.z); e.y = __expf(u0.w); F0[2 * q + 1] = e;
            e.x = __expf(u1.x); e.y = __expf(u1.y); F1[2 * q]     = e;
            e.x = __expf(u1.z); e.y = __expf(u1.w); F1[2 * q + 1] = e;
        }
    }

    const float* fb = feats + (size_t)base * CC;
    const int M      = len >> 1;     // fwd steps
    const int nB     = len - M;      // bwd steps (>= 1)
    const int nSteps = dir ? nB : M;

    // ---- init state: fwd a_0 = onehot(START);
    //      bwd c_0[j] = exp(trans[j][STOP]) * exp(f_{len-1}[j]) ----
    {
        float2 w;
        if (dir == 0) {
            w.x = (j0 == CC - 2) ? 1.0f : 0.0f;
            w.y = (j1 == CC - 2) ? 1.0f : 0.0f;
        } else {
            const float2 ff = *(const float2*)&fb[(size_t)(len - 1) * CC + j0];
            w.x = __expf(trans[(size_t)j0 * CC + (CC - 1)]) * __expf(ff.x);
            w.y = __expf(trans[(size_t)j1 * CC + (CC - 1)]) * __expf(ff.y);
        }
        *(float2*)&buf[0][j0] = w;
    }
    wait_lds();

    // ---- feats prefetch (PF deep): fwd walks up from 0, bwd down from len-2
    float2 fx[PF];
    #pragma unroll
    for (int k = 0; k < PF; ++k) {
        int tg = dir ? (len - 2 - k) : k;
        tg = (tg > 0) ? tg : 0;
        fx[k] = *(const float2*)&fb[(size_t)tg * CC + j0];
    }

    float S = 0.0f;                  // sum of applied log(c)
    const int nUp = (nSteps + 3) & ~3;

    for (int tc = 0; tc < nUp; tc += 4) {
        #pragma unroll
        for (int k = 0; k < 4; ++k) {
            const int it  = tc + k;
            const int par = k & 1;   // == it & 1
            const float* q = &buf[par][0];

            // whole-state broadcast read + full dot products (no reduce)
            v2f a0 = {0.f, 0.f}, a1 = {0.f, 0.f};
            v2f b0 = {0.f, 0.f}, b1 = {0.f, 0.f};
            float u0val = 1.0f;
            #pragma unroll
            for (int qq = 0; qq < 32; ++qq) {
                const float4 P = *(const float4*)(q + qq * 4);
                if (qq == 0) u0val = P.x;
                v2f U01; U01.x = P.x; U01.y = P.y;
                v2f U23; U23.x = P.z; U23.y = P.w;
                a0 = __builtin_elementwise_fma(F0[2 * qq],     U01, a0);
                a1 = __builtin_elementwise_fma(F0[2 * qq + 1], U23, a1);
                b0 = __builtin_elementwise_fma(F1[2 * qq],     U01, b0);
                b1 = __builtin_elementwise_fma(F1[2 * qq + 1], U23, b1);
            }
            a0 += a1; b0 += b1;
            const float s0 = a0.x + a0.y;
            const float s1 = b0.x + b0.y;

            // emission factor; bwd's LAST step writes the raw matvec (its
            // premultiplier belongs to the fwd side -> each feat counted once)
            const bool noMul = (dir != 0) && (it == nSteps - 1);
            const float e0f = noMul ? 1.0f : __expf(fx[k].x);
            const float e1f = noMul ? 1.0f : __expf(fx[k].y);

            float v0, v1;
            if (k == 3) {            // deferred rescale by current u[0]
                const float rinv = __builtin_amdgcn_rcpf(u0val);
                v0 = e0f * s0 * rinv;
                v1 = e1f * s1 * rinv;
            } else {
                v0 = e0f * s0;
                v1 = e1f * s1;
            }

            // prefetch feats for step it+PF (clamped; identical work per call)
            int tn = dir ? (len - 2 - (it + PF)) : (it + PF);
            tn = dir ? ((tn > 0) ? tn : 0) : ((tn < TT) ? tn : (TT - 1));
            fx[k] = *(const float2*)&fb[(size_t)tn * CC + j0];

            if (it < nSteps) {       // uniform branch
                if (k == 3) S += __logf(u0val);  // record exactly what was divided
                float2 w2; w2.x = v0; w2.y = v1;
                *(float2*)&buf[par ^ 1][j0] = w2;
            }
            // padded steps: no write, no S update -> state frozen, exact.
            wait_lds();              // write visible before next body's reads
        }
    }

    // ---- write final vector + log-scale sum to workspace ----
    const float2 uu = *(const float2*)&buf[nSteps & 1][j0];
    float* resv = ws + 16 + (size_t)bb * WS_STRIDE + dir * 128;
    *(float2*)&resv[j0] = uu;
    if (lane == 0) ws[16 + (size_t)bb * WS_STRIDE + 256 + dir] = S;
}

// Fused junction + final: one wave; thread handles 2 batch elements.
// r_b = log(sum_i aM[i]*bM[i]) + SF + SB - gold;  out = sum_b r_b / B.
__global__ void crf_epi(const float* __restrict__ ws, float* __restrict__ out)
{
    const int lane = threadIdx.x;    // 0..63
    float r = 0.0f;
    #pragma unroll
    for (int h = 0; h < 2; ++h) {
        const int b = lane * 2 + h;
        const float* base = ws + 16 + (size_t)b * WS_STRIDE;
        float dot = 0.0f;
        #pragma unroll 8
        for (int i = 0; i < 128; i += 4) {
            const float4 av = *(const float4*)&base[i];
            const float4 bv = *(const float4*)&base[128 + i];
            dot += av.x * bv.x + av.y * bv.y + av.z * bv.z + av.w * bv.w;
        }
        r += __logf(dot) + base[256] + base[257] - base[258];
    }
    #pragma unroll
    for (int o = 1; o <= 32; o <<= 1) r += __shfl_xor(r, o);
    if (lane == 0) out[0] = r * (1.0f / (float)BB);
}

extern "C" void kernel_launch(void* const* d_in, const int* in_sizes, int n_in,
                              void* d_out, int out_size, void* d_ws, size_t ws_size,
                              hipStream_t stream)
{
    const float* feats = (const float*)d_in[0];
    const int*   mask  = (const int*)d_in[1];
    const int*   tags  = (const int*)d_in[2];
    const float* trans = (const float*)d_in[3];
    float* out = (float*)d_out;
    float* ws  = (float*)d_ws;       // needs ~164 KB

    crf_scan<<<BB * 2, 64, 0, stream>>>(feats, mask, tags, trans, ws);
    crf_epi<<<1, 64, 0, stream>>>(ws, out);
}

// Round 7
// 378.467 us; speedup vs baseline: 1.0197x; 1.0197x over previous
//
#include <hip/hip_runtime.h>

// CRF NLL on MI355X, round 9: wave-autonomous scan, take 2 — FIX REGISTER
// PROMOTION. Round-8 failure: VGPR=172 proved the 256-VGPR E-fragment
// arrays went to scratch (~64 scratch loads/step -> 2980cy/step). Cause:
// arrays declared once, initialized under a runtime if(dir) -> alloca lives
// across the CFG merge -> SROA bails. Fix: template<int DIR> body, arrays
// declared INSIDE each instantiation with straight-line init (every index
// compile-time), split into 4x32-element allocas. One kernel, block-uniform
// dispatch (two launches would serialize fwd/bwd on the stream).
// Design per round 8: 256 blocks x 64 thr (1 wave); lane owns cols 2l,2l+1;
// per step: 32x ds_read_b128 uniform-address broadcast of the 128-float
// state -> 128 pk-FMA full dots (no reduce, no barrier) -> exp(feat)*dot
// (every-4th-step rescale by state[0]) -> ds_write_b64 -> lgkmcnt(0).

#define BB   128
#define TT   512
#define CC   128
#define PF   4
#define WS_STRIDE 320
// ws layout per batch bb at ws + 16 + bb*320:
//   [0:128) aM (fwd final)  [128:256) bM (bwd final)
//   [256] SF  [257] SB  [258] gold score
// total ws bytes: (16 + 128*320)*4 ~= 164 KB

typedef float v2f __attribute__((ext_vector_type(2)));

__device__ __forceinline__ void wait_lds() {
    // In-wave LDS visibility: drain ds ops; "memory" clobber keeps the
    // compiler from moving LDS accesses across it. vmcnt untouched (global
    // feats prefetch stays in flight).
    asm volatile("s_waitcnt lgkmcnt(0)" ::: "memory");
}

template<int DIR>
__device__ __forceinline__ void scan_body(
    const float* __restrict__ feats,
    const int*   __restrict__ mask,
    const int*   __restrict__ tags,
    const float* __restrict__ trans,
    float*       __restrict__ ws,
    float      (*buf)[CC])           // __shared__ [2][CC] ping-pong state
{
    const int bb   = blockIdx.x >> 1;
    const int lane = threadIdx.x;    // 0..63, one wave
    const int j0   = lane * 2;
    const int j1   = j0 + 1;
    const int base = bb * TT;

    // ---- sequence length (contiguous prefix mask) + gold score ----
    int len = 0;
    int mvals[8];
    #pragma unroll
    for (int c2 = 0; c2 < 8; ++c2) {
        mvals[c2] = mask[base + c2 * 64 + lane];
        len += __popcll(__ballot(mvals[c2] != 0));
    }
    if (DIR == 0) {                  // gold path scored by the fwd block only
        float sc = 0.0f;
        #pragma unroll
        for (int c2 = 0; c2 < 8; ++c2) {
            const int t = c2 * 64 + lane;
            if (mvals[c2]) {
                const int tg = tags[base + t];
                sc += feats[((size_t)(base + t)) * CC + tg];
                sc += (t == 0) ? trans[(CC - 2) * CC + tg]
                               : trans[tags[base + t - 1] * CC + tg];
                const int nm = (t == TT - 1) ? 0 : mask[base + t + 1];
                if (!nm) sc += trans[tg * CC + (CC - 1)];
            }
        }
        #pragma unroll
        for (int o = 1; o <= 32; o <<= 1) sc += __shfl_xor(sc, o);
        if (lane == 0) ws[16 + (size_t)bb * WS_STRIDE + 258] = sc;
    }

    // ---- E fragments in registers (4 x 32 v2f = 256 VGPR), straight-line
    //      compile-time init — no CFG merge, SROA-promotable.
    //  Dot step q consumes state u[4q..4q+3] as U01=(u[4q],u[4q+1]),
    //  U23=(u[4q+2],u[4q+3]):
    //   col j0: F0e[q]·U01 + F0o[q]·U23 ; col j1: F1e[q]·U01 + F1o[q]·U23
    //  fwd: F0e[q]=(E[4q][j0],E[4q+1][j0]) etc (column of E)
    //  bwd: F0e[q]=(E[j0][4q],E[j0][4q+1]) etc (row of E)
    v2f F0e[32], F0o[32], F1e[32], F1o[32];
    #pragma unroll
    for (int q = 0; q < 32; ++q) {
        v2f e;
        if (DIR == 0) {
            const float2 t0 = *(const float2*)&trans[(size_t)(4 * q    ) * CC + j0];
            const float2 t1 = *(const float2*)&trans[(size_t)(4 * q + 1) * CC + j0];
            const float2 t2 = *(const float2*)&trans[(size_t)(4 * q + 2) * CC + j0];
            const float2 t3 = *(const float2*)&trans[(size_t)(4 * q + 3) * CC + j0];
            e.x = __expf(t0.x); e.y = __expf(t1.x); F0e[q] = e;
            e.x = __expf(t2.x); e.y = __expf(t3.x); F0o[q] = e;
            e.x = __expf(t0.y); e.y = __expf(t1.y); F1e[q] = e;
            e.x = __expf(t2.y); e.y = __expf(t3.y); F1o[q] = e;
        } else {
            const float4 u0 = *(const float4*)&trans[(size_t)j0 * CC + 4 * q];
            const float4 u1 = *(const float4*)&trans[(size_t)j1 * CC + 4 * q];
            e.x = __expf(u0.x); e.y = __expf(u0.y); F0e[q] = e;
            e.x = __expf(u0.z); e.y = __expf(u0.w); F0o[q] = e;
            e.x = __expf(u1.x); e.y = __expf(u1.y); F1e[q] = e;
            e.x = __expf(u1.z); e.y = __expf(u1.w); F1o[q] = e;
        }
    }

    const float* fb = feats + (size_t)base * CC;
    const int M      = len >> 1;     // fwd steps
    const int nB     = len - M;      // bwd steps (>= 1)
    const int nSteps = DIR ? nB : M;

    // ---- init state: fwd a_0 = onehot(START);
    //      bwd c_0[j] = exp(trans[j][STOP]) * exp(f_{len-1}[j]) ----
    {
        float2 w;
        if (DIR == 0) {
            w.x = (j0 == CC - 2) ? 1.0f : 0.0f;
            w.y = (j1 == CC - 2) ? 1.0f : 0.0f;
        } else {
            const float2 ff = *(const float2*)&fb[(size_t)(len - 1) * CC + j0];
            w.x = __expf(trans[(size_t)j0 * CC + (CC - 1)]) * __expf(ff.x);
            w.y = __expf(trans[(size_t)j1 * CC + (CC - 1)]) * __expf(ff.y);
        }
        *(float2*)&buf[0][j0] = w;
    }
    wait_lds();

    // ---- feats prefetch (PF deep): fwd walks up from 0, bwd down from len-2
    float2 fx[PF];
    #pragma unroll
    for (int k = 0; k < PF; ++k) {
        int tg = DIR ? (len - 2 - k) : k;
        tg = (tg > 0) ? tg : 0;
        fx[k] = *(const float2*)&fb[(size_t)tg * CC + j0];
    }

    float S = 0.0f;                  // sum of applied log(c)
    const int nUp = (nSteps + 3) & ~3;

    for (int tc = 0; tc < nUp; tc += 4) {
        #pragma unroll
        for (int k = 0; k < 4; ++k) {
            const int it  = tc + k;
            const int par = k & 1;   // == it & 1
            const float* q = &buf[par][0];

            // whole-state broadcast read + full dot products (no reduce)
            v2f a0 = {0.f, 0.f}, a1 = {0.f, 0.f};
            v2f b0 = {0.f, 0.f}, b1 = {0.f, 0.f};
            float u0val = 1.0f;
            #pragma unroll
            for (int qq = 0; qq < 32; ++qq) {
                const float4 P = *(const float4*)(q + qq * 4);
                if (qq == 0) u0val = P.x;
                v2f U01; U01.x = P.x; U01.y = P.y;
                v2f U23; U23.x = P.z; U23.y = P.w;
                a0 = __builtin_elementwise_fma(F0e[qq], U01, a0);
                a1 = __builtin_elementwise_fma(F0o[qq], U23, a1);
                b0 = __builtin_elementwise_fma(F1e[qq], U01, b0);
                b1 = __builtin_elementwise_fma(F1o[qq], U23, b1);
            }
            a0 += a1; b0 += b1;
            const float s0 = a0.x + a0.y;
            const float s1 = b0.x + b0.y;

            // emission factor; bwd's LAST step writes the raw matvec (its
            // premultiplier belongs to the fwd side -> each feat counted once)
            const bool noMul = (DIR != 0) && (it == nSteps - 1);
            const float e0f = noMul ? 1.0f : __expf(fx[k].x);
            const float e1f = noMul ? 1.0f : __expf(fx[k].y);

            float v0, v1;
            if (k == 3) {            // deferred rescale by current state[0]
                const float rinv = __builtin_amdgcn_rcpf(u0val);
                v0 = e0f * s0 * rinv;
                v1 = e1f * s1 * rinv;
            } else {
                v0 = e0f * s0;
                v1 = e1f * s1;
            }

            // prefetch feats for step it+PF (clamped; identical work per call)
            int tn = DIR ? (len - 2 - (it + PF)) : (it + PF);
            tn = DIR ? ((tn > 0) ? tn : 0) : ((tn < TT) ? tn : (TT - 1));
            fx[k] = *(const float2*)&fb[(size_t)tn * CC + j0];

            if (it < nSteps) {       // uniform branch
                if (k == 3) S += __logf(u0val);  // record exactly what was divided
                float2 w2; w2.x = v0; w2.y = v1;
                *(float2*)&buf[par ^ 1][j0] = w2;
            }
            // padded steps: no write, no S update -> state frozen, exact.
            wait_lds();              // write visible before next body's reads
        }
    }

    // ---- write final vector + log-scale sum to workspace ----
    const float2 uu = *(const float2*)&buf[nSteps & 1][j0];
    float* resv = ws + 16 + (size_t)bb * WS_STRIDE + DIR * 128;
    *(float2*)&resv[j0] = uu;
    if (lane == 0) ws[16 + (size_t)bb * WS_STRIDE + 256 + DIR] = S;
}

__global__ __launch_bounds__(64, 1) void crf_scan(
    const float* __restrict__ feats,
    const int*   __restrict__ mask,
    const int*   __restrict__ tags,
    const float* __restrict__ trans,
    float*       __restrict__ ws)
{
    __shared__ __align__(16) float buf[2][CC];
    if (blockIdx.x & 1) scan_body<1>(feats, mask, tags, trans, ws, buf);
    else                scan_body<0>(feats, mask, tags, trans, ws, buf);
}

// Fused junction + final: one wave; thread handles 2 batch elements.
// r_b = log(sum_i aM[i]*bM[i]) + SF + SB - gold;  out = sum_b r_b / B.
__global__ void crf_epi(const float* __restrict__ ws, float* __restrict__ out)
{
    const int lane = threadIdx.x;    // 0..63
    float r = 0.0f;
    #pragma unroll
    for (int h = 0; h < 2; ++h) {
        const int b = lane * 2 + h;
        const float* base = ws + 16 + (size_t)b * WS_STRIDE;
        float dot = 0.0f;
        #pragma unroll 8
        for (int i = 0; i < 128; i += 4) {
            const float4 av = *(const float4*)&base[i];
            const float4 bv = *(const float4*)&base[128 + i];
            dot += av.x * bv.x + av.y * bv.y + av.z * bv.z + av.w * bv.w;
        }
        r += __logf(dot) + base[256] + base[257] - base[258];
    }
    #pragma unroll
    for (int o = 1; o <= 32; o <<= 1) r += __shfl_xor(r, o);
    if (lane == 0) out[0] = r * (1.0f / (float)BB);
}

extern "C" void kernel_launch(void* const* d_in, const int* in_sizes, int n_in,
                              void* d_out, int out_size, void* d_ws, size_t ws_size,
                              hipStream_t stream)
{
    const float* feats = (const float*)d_in[0];
    const int*   mask  = (const int*)d_in[1];
    const int*   tags  = (const int*)d_in[2];
    const float* trans = (const float*)d_in[3];
    float* out = (float*)d_out;
    float* ws  = (float*)d_ws;       // needs ~164 KB

    crf_scan<<<BB * 2, 64, 0, stream>>>(feats, mask, tags, trans, ws);
    crf_epi<<<1, 64, 0, stream>>>(ws, out);
}

// Round 8
// 378.305 us; speedup vs baseline: 1.0202x; 1.0004x over previous
//
#include <hip/hip_runtime.h>

// CRF NLL on MI355X, round 10: wave-autonomous scan, take 3 — NAMED-REGISTER
// E fragments. Rounds 8/9 failed with VGPR=172/176: SROA runs BEFORE loop
// unrolling, so any array indexed by a loop variable (F0e[qq]) is
// dynamically-indexed at promotion time -> alloca stays in scratch; the
// template<DIR>/straight-line-init fix was irrelevant. This round removes
// arrays entirely: 128 macro-generated NAMED v2f locals (F0e_0..F1o_31),
// init + dot expanded via R32() repetition macro -> pure SSA values, no
// alloca, promotion guaranteed.
// Design (verified exact in r8/r9, absmax 0): 256 blocks x 64 thr (1 wave);
// bb=bid>>1, dir=bid&1 (fwd/bwd split per round 7). Lane owns cols 2l,2l+1.
// Per step: 32x ds_read_b128 uniform-addr broadcast of the 128-float state
// -> 128 pk-FMA full dots (no reduce, no barrier) -> exp(feat)*dot
// (every-4th-step rescale by state[0]) -> ds_write_b64 -> lgkmcnt(0).

#define BB   128
#define TT   512
#define CC   128
#define PF   4
#define WS_STRIDE 320
// ws layout per batch bb at ws + 16 + bb*320:
//   [0:128) aM (fwd final)  [128:256) bM (bwd final)
//   [256] SF  [257] SB  [258] gold score
// total ws bytes: (16 + 128*320)*4 ~= 164 KB

typedef float v2f __attribute__((ext_vector_type(2)));

__device__ __forceinline__ void wait_lds() {
    // In-wave LDS visibility: drain ds ops; "memory" clobber keeps the
    // compiler from moving LDS accesses across it. vmcnt untouched (global
    // feats prefetch stays in flight).
    asm volatile("s_waitcnt lgkmcnt(0)" ::: "memory");
}

#define R32(X) X(0) X(1) X(2) X(3) X(4) X(5) X(6) X(7) \
               X(8) X(9) X(10) X(11) X(12) X(13) X(14) X(15) \
               X(16) X(17) X(18) X(19) X(20) X(21) X(22) X(23) \
               X(24) X(25) X(26) X(27) X(28) X(29) X(30) X(31)

template<int DIR>
__device__ __forceinline__ void scan_body(
    const float* __restrict__ feats,
    const int*   __restrict__ mask,
    const int*   __restrict__ tags,
    const float* __restrict__ trans,
    float*       __restrict__ ws,
    float      (*buf)[CC])           // __shared__ [2][CC] ping-pong state
{
    const int bb   = blockIdx.x >> 1;
    const int lane = threadIdx.x;    // 0..63, one wave
    const int j0   = lane * 2;
    const int j1   = j0 + 1;
    const int base = bb * TT;

    // ---- sequence length (contiguous prefix mask) + gold score ----
    int len = 0;
    int mvals[8];
    #pragma unroll
    for (int c2 = 0; c2 < 8; ++c2) {
        mvals[c2] = mask[base + c2 * 64 + lane];
        len += __popcll(__ballot(mvals[c2] != 0));
    }
    if (DIR == 0) {                  // gold path scored by the fwd block only
        float sc = 0.0f;
        #pragma unroll
        for (int c2 = 0; c2 < 8; ++c2) {
            const int t = c2 * 64 + lane;
            if (mvals[c2]) {
                const int tg = tags[base + t];
                sc += feats[((size_t)(base + t)) * CC + tg];
                sc += (t == 0) ? trans[(CC - 2) * CC + tg]
                               : trans[tags[base + t - 1] * CC + tg];
                const int nm = (t == TT - 1) ? 0 : mask[base + t + 1];
                if (!nm) sc += trans[tg * CC + (CC - 1)];
            }
        }
        #pragma unroll
        for (int o = 1; o <= 32; o <<= 1) sc += __shfl_xor(sc, o);
        if (lane == 0) ws[16 + (size_t)bb * WS_STRIDE + 258] = sc;
    }

    // ---- E fragments as 128 NAMED v2f locals (256 VGPR) — no arrays, no
    //      runtime indices, nothing for SROA to reject.
    //  Dot chunk q consumes state u[4q..4q+3] as U01=(u[4q],u[4q+1]),
    //  U23=(u[4q+2],u[4q+3]):
    //   col j0: F0e_q·U01 + F0o_q·U23 ; col j1: F1e_q·U01 + F1o_q·U23
    //  fwd: F0e_q=(E[4q][j0],E[4q+1][j0]) etc (column of E)
    //  bwd: F0e_q=(E[j0][4q],E[j0][4q+1]) etc (row of E)
#define DECLF(q) v2f F0e_##q, F0o_##q, F1e_##q, F1o_##q;
    R32(DECLF)
#undef DECLF

#define INITF(q) \
    if (DIR == 0) { \
        const float2 t0 = *(const float2*)&trans[(size_t)(4 * q    ) * CC + j0]; \
        const float2 t1 = *(const float2*)&trans[(size_t)(4 * q + 1) * CC + j0]; \
        const float2 t2 = *(const float2*)&trans[(size_t)(4 * q + 2) * CC + j0]; \
        const float2 t3 = *(const float2*)&trans[(size_t)(4 * q + 3) * CC + j0]; \
        F0e_##q.x = __expf(t0.x); F0e_##q.y = __expf(t1.x); \
        F0o_##q.x = __expf(t2.x); F0o_##q.y = __expf(t3.x); \
        F1e_##q.x = __expf(t0.y); F1e_##q.y = __expf(t1.y); \
        F1o_##q.x = __expf(t2.y); F1o_##q.y = __expf(t3.y); \
    } else { \
        const float4 u0 = *(const float4*)&trans[(size_t)j0 * CC + 4 * q]; \
        const float4 u1 = *(const float4*)&trans[(size_t)j1 * CC + 4 * q]; \
        F0e_##q.x = __expf(u0.x); F0e_##q.y = __expf(u0.y); \
        F0o_##q.x = __expf(u0.z); F0o_##q.y = __expf(u0.w); \
        F1e_##q.x = __expf(u1.x); F1e_##q.y = __expf(u1.y); \
        F1o_##q.x = __expf(u1.z); F1o_##q.y = __expf(u1.w); \
    }
    R32(INITF)
#undef INITF

    const float* fb = feats + (size_t)base * CC;
    const int M      = len >> 1;     // fwd steps
    const int nB     = len - M;      // bwd steps (>= 1)
    const int nSteps = DIR ? nB : M;

    // ---- init state: fwd a_0 = onehot(START);
    //      bwd c_0[j] = exp(trans[j][STOP]) * exp(f_{len-1}[j]) ----
    {
        float2 w;
        if (DIR == 0) {
            w.x = (j0 == CC - 2) ? 1.0f : 0.0f;
            w.y = (j1 == CC - 2) ? 1.0f : 0.0f;
        } else {
            const float2 ff = *(const float2*)&fb[(size_t)(len - 1) * CC + j0];
            w.x = __expf(trans[(size_t)j0 * CC + (CC - 1)]) * __expf(ff.x);
            w.y = __expf(trans[(size_t)j1 * CC + (CC - 1)]) * __expf(ff.y);
        }
        *(float2*)&buf[0][j0] = w;
    }
    wait_lds();

    // ---- feats prefetch (PF deep): fwd walks up from 0, bwd down from len-2
    float2 fx[PF];
    #pragma unroll
    for (int k = 0; k < PF; ++k) {
        int tg = DIR ? (len - 2 - k) : k;
        tg = (tg > 0) ? tg : 0;
        fx[k] = *(const float2*)&fb[(size_t)tg * CC + j0];
    }

    float S = 0.0f;                  // sum of applied log(c)
    const int nUp = (nSteps + 3) & ~3;

    for (int tc = 0; tc < nUp; tc += 4) {
        #pragma unroll
        for (int k = 0; k < 4; ++k) {
            const int it  = tc + k;
            const int par = k & 1;   // == it & 1
            const float4* qp = (const float4*)&buf[par][0];

            // whole-state broadcast read + full dot products (no reduce)
            v2f a0 = {0.f, 0.f}, a1 = {0.f, 0.f};
            v2f b0 = {0.f, 0.f}, b1 = {0.f, 0.f};
            float u0val = 1.0f;
#define DOTF(q) { \
            const float4 P = qp[q]; \
            if (q == 0) u0val = P.x; \
            v2f U01; U01.x = P.x; U01.y = P.y; \
            v2f U23; U23.x = P.z; U23.y = P.w; \
            a0 = __builtin_elementwise_fma(F0e_##q, U01, a0); \
            a1 = __builtin_elementwise_fma(F0o_##q, U23, a1); \
            b0 = __builtin_elementwise_fma(F1e_##q, U01, b0); \
            b1 = __builtin_elementwise_fma(F1o_##q, U23, b1); \
        }
            R32(DOTF)
#undef DOTF
            a0 += a1; b0 += b1;
            const float s0 = a0.x + a0.y;
            const float s1 = b0.x + b0.y;

            // emission factor; bwd's LAST step writes the raw matvec (its
            // premultiplier belongs to the fwd side -> each feat counted once)
            const bool noMul = (DIR != 0) && (it == nSteps - 1);
            const float e0f = noMul ? 1.0f : __expf(fx[k].x);
            const float e1f = noMul ? 1.0f : __expf(fx[k].y);

            float v0, v1;
            if (k == 3) {            // deferred rescale by current state[0]
                const float rinv = __builtin_amdgcn_rcpf(u0val);
                v0 = e0f * s0 * rinv;
                v1 = e1f * s1 * rinv;
            } else {
                v0 = e0f * s0;
                v1 = e1f * s1;
            }

            // prefetch feats for step it+PF (clamped; identical work per call)
            int tn = DIR ? (len - 2 - (it + PF)) : (it + PF);
            tn = DIR ? ((tn > 0) ? tn : 0) : ((tn < TT) ? tn : (TT - 1));
            fx[k] = *(const float2*)&fb[(size_t)tn * CC + j0];

            if (it < nSteps) {       // uniform branch
                if (k == 3) S += __logf(u0val);  // record exactly what was divided
                float2 w2; w2.x = v0; w2.y = v1;
                *(float2*)&buf[par ^ 1][j0] = w2;
            }
            // padded steps: no write, no S update -> state frozen, exact.
            wait_lds();              // write visible before next body's reads
        }
    }

    // ---- write final vector + log-scale sum to workspace ----
    const float2 uu = *(const float2*)&buf[nSteps & 1][j0];
    float* resv = ws + 16 + (size_t)bb * WS_STRIDE + DIR * 128;
    *(float2*)&resv[j0] = uu;
    if (lane == 0) ws[16 + (size_t)bb * WS_STRIDE + 256 + DIR] = S;
}

__global__ __launch_bounds__(64, 1) void crf_scan(
    const float* __restrict__ feats,
    const int*   __restrict__ mask,
    const int*   __restrict__ tags,
    const float* __restrict__ trans,
    float*       __restrict__ ws)
{
    __shared__ __align__(16) float buf[2][CC];
    if (blockIdx.x & 1) scan_body<1>(feats, mask, tags, trans, ws, buf);
    else                scan_body<0>(feats, mask, tags, trans, ws, buf);
}

// Fused junction + final: one wave; thread handles 2 batch elements.
// r_b = log(sum_i aM[i]*bM[i]) + SF + SB - gold;  out = sum_b r_b / B.
__global__ void crf_epi(const float* __restrict__ ws, float* __restrict__ out)
{
    const int lane = threadIdx.x;    // 0..63
    float r = 0.0f;
    #pragma unroll
    for (int h = 0; h < 2; ++h) {
        const int b = lane * 2 + h;
        const float* base = ws + 16 + (size_t)b * WS_STRIDE;
        float dot = 0.0f;
        #pragma unroll 8
        for (int i = 0; i < 128; i += 4) {
            const float4 av = *(const float4*)&base[i];
            const float4 bv = *(const float4*)&base[128 + i];
            dot += av.x * bv.x + av.y * bv.y + av.z * bv.z + av.w * bv.w;
        }
        r += __logf(dot) + base[256] + base[257] - base[258];
    }
    #pragma unroll
    for (int o = 1; o <= 32; o <<= 1) r += __shfl_xor(r, o);
    if (lane == 0) out[0] = r * (1.0f / (float)BB);
}

extern "C" void kernel_launch(void* const* d_in, const int* in_sizes, int n_in,
                              void* d_out, int out_size, void* d_ws, size_t ws_size,
                              hipStream_t stream)
{
    const float* feats = (const float*)d_in[0];
    const int*   mask  = (const int*)d_in[1];
    const int*   tags  = (const int*)d_in[2];
    const float* trans = (const float*)d_in[3];
    float* out = (float*)d_out;
    float* ws  = (float*)d_ws;       // needs ~164 KB

    crf_scan<<<BB * 2, 64, 0, stream>>>(feats, mask, tags, trans, ws);
    crf_epi<<<1, 64, 0, stream>>>(ws, out);
}

// Round 9
// 197.895 us; speedup vs baseline: 1.9502x; 1.9116x over previous
//
#include <hip/hip_runtime.h>

// CRF NLL on MI355X, round 11: one-column-per-thread scan — register-resident
// E at HALF the pressure. Rounds 8-10 proved (VGPR=176, identical dur, even
// with pure named SSA values) that a 256-VGPR loop-invariant set gets spilled
// by the register allocator itself. This round: 128 threads/block, thread
// owns ONE column j=tid; its E column = 64 named v2f = 128 VGPR; total
// demand ~190 < 256 arch cap -> RA can comply.
// Kept: barrier-free-style full in-lane dots (no cross-lane reduce, no
// swizzle), uniform-addr broadcast ds_read_b128 of the whole state, fwd/bwd
// split across blocks (bb=bid>>1, dir=bid&1; junction in epilogue kernel),
// deferred every-4-step rescale, PF=4 feats prefetch (1 float/lane/step,
// coalesced 512B/block). New cost: one 2-wave bar_nodrain per step (cheap
// vs round-7's 8-wave barrier + reduce).
// Per step: 32x ds_read_b128 broadcast -> 32 pk-FMA -> exp(feat)*dot
// (every-4th-step rescale by state[0]) -> ds_write_b32 -> lgkmcnt+barrier.

#define BB   128
#define TT   512
#define CC   128
#define NTHR 128
#define PF   4
#define WS_STRIDE 320
// ws layout per batch bb at ws + 16 + bb*320:
//   [0:128) aM (fwd final)  [128:256) bM (bwd final)
//   [256] SF  [257] SB  [258] gold score
// total ws bytes: (16 + 128*320)*4 ~= 164 KB

typedef float v2f __attribute__((ext_vector_type(2)));

__device__ __forceinline__ void bar_nodrain() {
    // LDS-visibility barrier that does NOT drain vmcnt (global feats prefetch
    // stays in flight). "memory" clobber stops compiler reordering across it.
    asm volatile("s_waitcnt lgkmcnt(0)\n\ts_barrier" ::: "memory");
}

#define R32(X) X(0) X(1) X(2) X(3) X(4) X(5) X(6) X(7) \
               X(8) X(9) X(10) X(11) X(12) X(13) X(14) X(15) \
               X(16) X(17) X(18) X(19) X(20) X(21) X(22) X(23) \
               X(24) X(25) X(26) X(27) X(28) X(29) X(30) X(31)

template<int DIR>
__device__ __forceinline__ void scan_body(
    const float* __restrict__ feats,
    const int*   __restrict__ mask,
    const int*   __restrict__ tags,
    const float* __restrict__ trans,
    float*       __restrict__ ws,
    float      (*buf)[CC],           // __shared__ [2][CC] ping-pong state
    float*       wred)               // __shared__ [2]
{
    const int bb  = blockIdx.x >> 1;
    const int tid = threadIdx.x;     // 0..127; owns column j = tid
    const int j   = tid;
    const int wv  = tid >> 6;        // wave id (0/1)
    const int base = bb * TT;

    // ---- sequence length (contiguous prefix mask; 128 thr x 4 chunks) ----
    int mv[4];
    #pragma unroll
    for (int c = 0; c < 4; ++c) mv[c] = mask[base + c * NTHR + tid];
    int len = 0;
    #pragma unroll
    for (int c = 0; c < 4; ++c) len += __syncthreads_count(mv[c]);

    // ---- gold-path score (fwd block only; off the scan critical path) ----
    if (DIR == 0) {
        float sc = 0.0f;
        #pragma unroll
        for (int c = 0; c < 4; ++c) {
            const int t = c * NTHR + tid;
            if (mv[c]) {
                const int tg = tags[base + t];
                sc += feats[((size_t)(base + t)) * CC + tg];
                sc += (t == 0) ? trans[(CC - 2) * CC + tg]
                               : trans[tags[base + t - 1] * CC + tg];
                const int nm = (t == TT - 1) ? 0 : mask[base + t + 1];
                if (!nm) sc += trans[tg * CC + (CC - 1)];
            }
        }
        #pragma unroll
        for (int o = 1; o <= 32; o <<= 1) sc += __shfl_xor(sc, o);
        if ((tid & 63) == 0) wred[wv] = sc;
        __syncthreads();
        if (tid == 0) ws[16 + (size_t)bb * WS_STRIDE + 258] = wred[0] + wred[1];
    }

    // ---- E column in 64 NAMED v2f (128 VGPR): chunk q pairs with state
    //      u[4q..4q+3]:  dot += Ea_q·(u[4q],u[4q+1]) + Eb_q·(u[4q+2],u[4q+3])
    //  fwd: Ea_q=(E[4q][j],E[4q+1][j])       (column j of E; coalesced rows)
    //  bwd: Ea_q=(E[j][4q],E[j][4q+1])       (row j of E; float4 loads)
#define DECLF(q) v2f Ea_##q, Eb_##q;
    R32(DECLF)
#undef DECLF
#define INITF(q) \
    if (DIR == 0) { \
        const float t0 = trans[(size_t)(4 * q    ) * CC + j]; \
        const float t1 = trans[(size_t)(4 * q + 1) * CC + j]; \
        const float t2 = trans[(size_t)(4 * q + 2) * CC + j]; \
        const float t3 = trans[(size_t)(4 * q + 3) * CC + j]; \
        Ea_##q.x = __expf(t0); Ea_##q.y = __expf(t1); \
        Eb_##q.x = __expf(t2); Eb_##q.y = __expf(t3); \
    } else { \
        const float4 u = *(const float4*)&trans[(size_t)j * CC + 4 * q]; \
        Ea_##q.x = __expf(u.x); Ea_##q.y = __expf(u.y); \
        Eb_##q.x = __expf(u.z); Eb_##q.y = __expf(u.w); \
    }
    R32(INITF)
#undef INITF

    const float* fb = feats + (size_t)base * CC;
    const int M      = len >> 1;     // fwd steps
    const int nB     = len - M;      // bwd steps (>= 1)
    const int nSteps = DIR ? nB : M;

    // ---- init state: fwd a_0 = onehot(START);
    //      bwd c_0[j] = exp(trans[j][STOP]) * exp(f_{len-1}[j]) ----
    if (DIR == 0) {
        buf[0][j] = (j == CC - 2) ? 1.0f : 0.0f;
    } else {
        buf[0][j] = __expf(trans[(size_t)j * CC + (CC - 1)])
                  * __expf(fb[(size_t)(len - 1) * CC + j]);
    }

    // ---- feats prefetch (PF deep, 1 float/lane): fwd t up from 0,
    //      bwd t down from len-2 ----
    float fx[PF];
    #pragma unroll
    for (int k = 0; k < PF; ++k) {
        int tg = DIR ? (len - 2 - k) : k;
        tg = (tg > 0) ? tg : 0;
        fx[k] = fb[(size_t)tg * CC + j];
    }

    bar_nodrain();                   // state init visible to both waves

    float S = 0.0f;                  // sum of applied log(c)
    const int nUp = (nSteps + 3) & ~3;

    for (int tc = 0; tc < nUp; tc += 4) {
        #pragma unroll
        for (int k = 0; k < 4; ++k) {
            const int it  = tc + k;
            const int par = k & 1;   // == it & 1
            const float4* qp = (const float4*)&buf[par][0];

            // whole-state broadcast read + full in-lane dot (no reduce)
            v2f a0 = {0.f, 0.f}, a1 = {0.f, 0.f};
            float u0val = 1.0f;
#define DOTF(q) { \
            const float4 P = qp[q]; \
            if (q == 0) u0val = P.x; \
            v2f U01; U01.x = P.x; U01.y = P.y; \
            v2f U23; U23.x = P.z; U23.y = P.w; \
            a0 = __builtin_elementwise_fma(Ea_##q, U01, a0); \
            a1 = __builtin_elementwise_fma(Eb_##q, U23, a1); \
        }
            R32(DOTF)
#undef DOTF
            a0 += a1;
            const float s = a0.x + a0.y;

            // emission factor; bwd's LAST step writes the raw matvec (its
            // premultiplier belongs to the fwd side -> each feat counted once)
            const bool noMul = (DIR != 0) && (it == nSteps - 1);
            const float ef = noMul ? 1.0f : __expf(fx[k]);

            float v;
            if (k == 3) {            // deferred rescale by current state[0]
                v = ef * s * __builtin_amdgcn_rcpf(u0val);
            } else {
                v = ef * s;
            }

            // prefetch feats for step it+PF (clamped; identical work per call)
            int tn = DIR ? (len - 2 - (it + PF)) : (it + PF);
            tn = DIR ? ((tn > 0) ? tn : 0) : ((tn < TT) ? tn : (TT - 1));
            fx[k] = fb[(size_t)tn * CC + j];

            if (it < nSteps) {       // uniform branch
                if (k == 3) S += __logf(u0val);  // record exactly what was divided
                buf[par ^ 1][j] = v; // 64 consecutive dwords/wave: 2-way, free
            }
            // padded steps: no write, no S update -> state frozen, exact.
            bar_nodrain();           // both waves' writes visible for next read
        }
    }

    // ---- write final vector + log-scale sum to workspace ----
    // buf[nSteps&1][j] was written by THIS thread (or is its own init) ->
    // no cross-thread dependency; loop's trailing barrier already executed.
    float* resv = ws + 16 + (size_t)bb * WS_STRIDE + DIR * 128;
    resv[j] = buf[nSteps & 1][j];
    if (tid == 0) ws[16 + (size_t)bb * WS_STRIDE + 256 + DIR] = S;
}

__global__ __launch_bounds__(NTHR, 1) void crf_scan(
    const float* __restrict__ feats,
    const int*   __restrict__ mask,
    const int*   __restrict__ tags,
    const float* __restrict__ trans,
    float*       __restrict__ ws)
{
    __shared__ __align__(16) float buf[2][CC];
    __shared__ float wred[2];
    if (blockIdx.x & 1) scan_body<1>(feats, mask, tags, trans, ws, buf, wred);
    else                scan_body<0>(feats, mask, tags, trans, ws, buf, wred);
}

// Fused junction + final: one wave; thread handles 2 batch elements.
// r_b = log(sum_i aM[i]*bM[i]) + SF + SB - gold;  out = sum_b r_b / B.
__global__ void crf_epi(const float* __restrict__ ws, float* __restrict__ out)
{
    const int lane = threadIdx.x;    // 0..63
    float r = 0.0f;
    #pragma unroll
    for (int h = 0; h < 2; ++h) {
        const int b = lane * 2 + h;
        const float* base = ws + 16 + (size_t)b * WS_STRIDE;
        float dot = 0.0f;
        #pragma unroll 8
        for (int i = 0; i < 128; i += 4) {
            const float4 av = *(const float4*)&base[i];
            const float4 bv = *(const float4*)&base[128 + i];
            dot += av.x * bv.x + av.y * bv.y + av.z * bv.z + av.w * bv.w;
        }
        r += __logf(dot) + base[256] + base[257] - base[258];
    }
    #pragma unroll
    for (int o = 1; o <= 32; o <<= 1) r += __shfl_xor(r, o);
    if (lane == 0) out[0] = r * (1.0f / (float)BB);
}

extern "C" void kernel_launch(void* const* d_in, const int* in_sizes, int n_in,
                              void* d_out, int out_size, void* d_ws, size_t ws_size,
                              hipStream_t stream)
{
    const float* feats = (const float*)d_in[0];
    const int*   mask  = (const int*)d_in[1];
    const int*   tags  = (const int*)d_in[2];
    const float* trans = (const float*)d_in[3];
    float* out = (float*)d_out;
    float* ws  = (float*)d_ws;       // needs ~164 KB

    crf_scan<<<BB * 2, NTHR, 0, stream>>>(feats, mask, tags, trans, ws);
    crf_epi<<<1, 64, 0, stream>>>(ws, out);
}

// Round 10
// 183.637 us; speedup vs baseline: 2.1016x; 1.0776x over previous
//
#include <hip/hip_runtime.h>

// CRF NLL on MI355X, round 12: round-7 structure with HALVED LDS traffic.
// RA verdict from r8-r11 (VGPR 172/176/176/132, step never < 1228cy): hipcc
// will not hold a >=128-VGPR loop-invariant set across a barrier loop ->
// broadcast-dot design abandoned. This round tunes the PROVEN r7 design:
// 512 thr, but 32 teams x 16 subs (4 cols/team, 8-row slice/sub) instead of
// 64x8: per-step LDS state traffic 32KB -> 16KB (~256 -> ~128cy of the
// ~865cy step), per-lane MACs unchanged (16 pk-FMA = the 32-MAC minimum).
// Costs: red16 (4 DPP hops vs 3), 4 exps (vs 2). Chunk-staggered reads
// (cA=2s+(s>>3), cB=2s+1-(s>>3)) put each read's 16 active chunks on all 8
// bank-quad slots exactly 2x -> 2-way aliasing, free (m136).
// Kept verbatim (verified absmax 0 five times): fwd/bwd split across blocks
// (bb=bid>>1, dir=bid&1), deferred every-4-step rescale, PF=4 prefetch,
// no-drain barrier, per-batch ws slots (no memset/atomics), fused epilogue.

#define BB   128
#define TT   512
#define CC   128
#define NTHR 512
#define PF   4
#define WS_STRIDE 320
// ws layout per batch bb at ws + 16 + bb*320:
//   [0:128) aM (fwd final)  [128:256) bM (bwd final)
//   [256] SF  [257] SB  [258] gold score
// total ws bytes: (16 + 128*320)*4 ~= 164 KB

typedef float v2f __attribute__((ext_vector_type(2)));

__device__ __forceinline__ void bar_nodrain() {
    // LDS-visibility barrier that does NOT drain vmcnt (global feats prefetch
    // stays in flight). "memory" clobber stops compiler reordering across it.
    asm volatile("s_waitcnt lgkmcnt(0)\n\ts_barrier" ::: "memory");
}

template<int CTRL>
__device__ __forceinline__ float dpp_xadd(float x) {
    const int y = __builtin_amdgcn_update_dpp(0, __float_as_int(x), CTRL, 0xF, 0xF, true);
    return x + __int_as_float(y);
}

// Sum across each aligned group of 16 lanes at VALU speed.
__device__ __forceinline__ float red16(float x) {
    x = dpp_xadd<0xB1>(x);    // quad_perm(1,0,3,2): + lane^1
    x = dpp_xadd<0x4E>(x);    // quad_perm(2,3,0,1): + lane^2
    x = dpp_xadd<0x141>(x);   // row_half_mirror: folds each 8
    x = dpp_xadd<0x140>(x);   // row_mirror: folds the two 8s -> full 16
    return x;
}

template<int DIR>
__device__ __forceinline__ void scan_body(
    const float* __restrict__ feats,
    const int*   __restrict__ mask,
    const int*   __restrict__ tags,
    const float* __restrict__ trans,
    float*       __restrict__ ws,
    float      (*buf)[CC],           // __shared__ [2][CC] ping-pong state
    float*       wred)               // __shared__ [8]
{
    const int bb   = blockIdx.x >> 1;
    const int tid  = threadIdx.x;
    const int team = tid >> 4;       // 32 teams: cols 4*team..4*team+3
    const int sub  = tid & 15;       // 8-row slice of the reduction axis
    const int j0   = team * 4;
    const int wid  = tid >> 6;

    // ---- sequence length (contiguous prefix mask; tid spans T exactly) ----
    const int myM = mask[bb * TT + tid];
    const int len = __syncthreads_count(myM);

    // ---- gold-path score (fwd block only; off the scan critical path) ----
    if (DIR == 0) {
        float sc = 0.0f;
        if (myM) {
            const int tg = tags[bb * TT + tid];
            sc += feats[((size_t)(bb * TT + tid)) * CC + tg];
            sc += (tid == 0) ? trans[(CC - 2) * CC + tg]
                             : trans[tags[bb * TT + tid - 1] * CC + tg];
            const int nm = (tid == TT - 1) ? 0 : mask[bb * TT + tid + 1];
            if (!nm) sc += trans[tg * CC + (CC - 1)];
        }
        #pragma unroll
        for (int o = 1; o <= 32; o <<= 1) sc += __shfl_xor(sc, o);
        if ((tid & 63) == 0) wred[wid] = sc;
        __syncthreads();
        if (tid == 0) {
            float s = 0.0f;
            #pragma unroll
            for (int k = 0; k < 8; ++k) s += wred[k];
            ws[16 + (size_t)bb * WS_STRIDE + 258] = s;
        }
    }

    // ---- chunk indices (16B chunks of the 512B state vector). Stagger so
    //      each read instruction's 16 distinct chunks land on all 8 bank-quad
    //      slots exactly 2x (2-way aliasing = free). {cA,cB} == {2s, 2s+1}.
    const int cA = 2 * sub + (sub >> 3);
    const int cB = 2 * sub + 1 - (sub >> 3);
    const int rA = cA * 4;           // first row of chunk A
    const int rB = cB * 4;           // first row of chunk B

    // ---- E fragments (16 v2f = 32 VGPR, proven-safe size):
    //  col c: dot += EA[c]·(P.x,P.y) + EA2[c]·(P.z,P.w)
    //             + EB[c]·(Q.x,Q.y) + EB2[c]·(Q.z,Q.w)
    //  where P = state chunk cA (u[rA..rA+3]), Q = chunk cB.
    //  fwd: EA[c]=(E[rA][j0+c],E[rA+1][j0+c]) (column of E)
    //  bwd: EA[c]=(E[j0+c][rA],E[j0+c][rA+1]) (row of E)
    v2f EA[4], EA2[4], EB[4], EB2[4];
    if (DIR == 0) {
        const float4 a0 = *(const float4*)&trans[(size_t)(rA    ) * CC + j0];
        const float4 a1 = *(const float4*)&trans[(size_t)(rA + 1) * CC + j0];
        const float4 a2 = *(const float4*)&trans[(size_t)(rA + 2) * CC + j0];
        const float4 a3 = *(const float4*)&trans[(size_t)(rA + 3) * CC + j0];
        const float4 b0 = *(const float4*)&trans[(size_t)(rB    ) * CC + j0];
        const float4 b1 = *(const float4*)&trans[(size_t)(rB + 1) * CC + j0];
        const float4 b2 = *(const float4*)&trans[(size_t)(rB + 2) * CC + j0];
        const float4 b3 = *(const float4*)&trans[(size_t)(rB + 3) * CC + j0];
        const float* p0 = (const float*)&a0; const float* p1 = (const float*)&a1;
        const float* p2 = (const float*)&a2; const float* p3 = (const float*)&a3;
        const float* q0 = (const float*)&b0; const float* q1 = (const float*)&b1;
        const float* q2 = (const float*)&b2; const float* q3 = (const float*)&b3;
        #pragma unroll
        for (int c = 0; c < 4; ++c) {
            v2f e;
            e.x = __expf(p0[c]); e.y = __expf(p1[c]); EA[c]  = e;
            e.x = __expf(p2[c]); e.y = __expf(p3[c]); EA2[c] = e;
            e.x = __expf(q0[c]); e.y = __expf(q1[c]); EB[c]  = e;
            e.x = __expf(q2[c]); e.y = __expf(q3[c]); EB2[c] = e;
        }
    } else {
        #pragma unroll
        for (int c = 0; c < 4; ++c) {
            const float4 ua = *(const float4*)&trans[(size_t)(j0 + c) * CC + rA];
            const float4 ub = *(const float4*)&trans[(size_t)(j0 + c) * CC + rB];
            v2f e;
            e.x = __expf(ua.x); e.y = __expf(ua.y); EA[c]  = e;
            e.x = __expf(ua.z); e.y = __expf(ua.w); EA2[c] = e;
            e.x = __expf(ub.x); e.y = __expf(ub.y); EB[c]  = e;
            e.x = __expf(ub.z); e.y = __expf(ub.w); EB2[c] = e;
        }
    }

    const float* fb = feats + (size_t)(bb * TT) * CC;
    const int M      = len >> 1;     // fwd steps
    const int nB     = len - M;      // bwd steps (>= 1)
    const int nSteps = DIR ? nB : M;

    // ---- init state: fwd a_0 = onehot(START);
    //      bwd c_0[j] = exp(trans[j][STOP]) * exp(f_{len-1}[j]) ----
    if (tid < CC) {
        if (DIR == 0) {
            buf[0][tid] = (tid == CC - 2) ? 1.0f : 0.0f;
        } else {
            buf[0][tid] = __expf(trans[(size_t)tid * CC + (CC - 1)])
                        * __expf(fb[(size_t)(len - 1) * CC + tid]);
        }
    }

    // ---- feats prefetch (PF deep, float4 of the team's 4 cols):
    //      fwd walks t up from 0; bwd walks down from len-2 ----
    float4 fx[PF];
    #pragma unroll
    for (int k = 0; k < PF; ++k) {
        int tg = DIR ? (len - 2 - k) : k;
        tg = (tg > 0) ? tg : 0;
        fx[k] = *(const float4*)&fb[(size_t)tg * CC + j0];
    }

    // per-parity chunk pointers (no per-step address math)
    const char* bufc = (const char*)&buf[0][0];
    const float4* qA0 = (const float4*)(bufc + cA * 16);
    const float4* qB0 = (const float4*)(bufc + cB * 16);
    const float4* qA1 = (const float4*)(bufc + CC * 4 + cA * 16);
    const float4* qB1 = (const float4*)(bufc + CC * 4 + cB * 16);

    float S = 0.0f;                  // sum of applied log(c)
    const int nUp = (nSteps + 3) & ~3;

    for (int tc = 0; tc < nUp; tc += 4) {
        #pragma unroll
        for (int k = 0; k < 4; ++k) {
            const int it  = tc + k;
            const int par = k & 1;   // == it & 1
            bar_nodrain();           // buf[par] now visible
            const float4 P = *(par ? qA1 : qA0);
            const float4 Q = *(par ? qB1 : qB0);
            float cval = 1.0f;
            if (k == 3) cval = buf[1][0];   // current state[0]; broadcast read

            v2f U01; U01.x = P.x; U01.y = P.y;
            v2f U23; U23.x = P.z; U23.y = P.w;
            v2f V01; V01.x = Q.x; V01.y = Q.y;
            v2f V23; V23.x = Q.z; V23.y = Q.w;

            float s[4];
            #pragma unroll
            for (int c = 0; c < 4; ++c) {
                v2f acc = {0.f, 0.f};
                acc = __builtin_elementwise_fma(EA[c],  U01, acc);
                acc = __builtin_elementwise_fma(EA2[c], U23, acc);
                acc = __builtin_elementwise_fma(EB[c],  V01, acc);
                acc = __builtin_elementwise_fma(EB2[c], V23, acc);
                s[c] = red16(acc.x + acc.y);
            }

            // emission factor; bwd's LAST step writes the raw matvec (its
            // premultiplier belongs to the fwd side -> each feat counted once)
            const bool noMul = (DIR != 0) && (it == nSteps - 1);
            const float* fxp = (const float*)&fx[k];
            float v[4];
            if (k == 3) {            // deferred rescale by current state[0]
                const float rinv = __builtin_amdgcn_rcpf(cval);
                #pragma unroll
                for (int c = 0; c < 4; ++c)
                    v[c] = (noMul ? 1.0f : __expf(fxp[c])) * s[c] * rinv;
            } else {
                #pragma unroll
                for (int c = 0; c < 4; ++c)
                    v[c] = (noMul ? 1.0f : __expf(fxp[c])) * s[c];
            }

            // prefetch feats for step it+PF (clamped; identical work per call)
            int tn = DIR ? (len - 2 - (it + PF)) : (it + PF);
            tn = DIR ? ((tn > 0) ? tn : 0) : ((tn < TT) ? tn : (TT - 1));
            fx[k] = *(const float4*)&fb[(size_t)tn * CC + j0];

            if (it < nSteps) {       // uniform branch
                if (k == 3) S += __logf(cval);  // record exactly what was divided
                if (sub == 0) {
                    float4 w4;
                    w4.x = v[0]; w4.y = v[1]; w4.z = v[2]; w4.w = v[3];
                    *(float4*)&buf[par ^ 1][j0] = w4;   // 32 lanes, 16B aligned
                }
            }
            // frozen steps: no write, no S update -> state stays exact.
        }
    }

    // ---- write final vector + log-scale sum to workspace ----
    bar_nodrain();                   // init/loop writes visible (covers len==1)
    float* resv = ws + 16 + (size_t)bb * WS_STRIDE + DIR * 128;
    if (sub == 0)
        *(float4*)&resv[j0] = *(const float4*)&buf[nSteps & 1][j0];
    if (tid == 0) ws[16 + (size_t)bb * WS_STRIDE + 256 + DIR] = S;
}

__global__ __launch_bounds__(NTHR) void crf_scan(
    const float* __restrict__ feats,
    const int*   __restrict__ mask,
    const int*   __restrict__ tags,
    const float* __restrict__ trans,
    float*       __restrict__ ws)
{
    __shared__ __align__(16) float buf[2][CC];
    __shared__ float wred[8];
    if (blockIdx.x & 1) scan_body<1>(feats, mask, tags, trans, ws, buf, wred);
    else                scan_body<0>(feats, mask, tags, trans, ws, buf, wred);
}

// Fused junction + final: one wave; thread handles 2 batch elements.
// r_b = log(sum_i aM[i]*bM[i]) + SF + SB - gold;  out = sum_b r_b / B.
__global__ void crf_epi(const float* __restrict__ ws, float* __restrict__ out)
{
    const int lane = threadIdx.x;    // 0..63
    float r = 0.0f;
    #pragma unroll
    for (int h = 0; h < 2; ++h) {
        const int b = lane * 2 + h;
        const float* base = ws + 16 + (size_t)b * WS_STRIDE;
        float dot = 0.0f;
        #pragma unroll 8
        for (int i = 0; i < 128; i += 4) {
            const float4 av = *(const float4*)&base[i];
            const float4 bv = *(const float4*)&base[128 + i];
            dot += av.x * bv.x + av.y * bv.y + av.z * bv.z + av.w * bv.w;
        }
        r += __logf(dot) + base[256] + base[257] - base[258];
    }
    #pragma unroll
    for (int o = 1; o <= 32; o <<= 1) r += __shfl_xor(r, o);
    if (lane == 0) out[0] = r * (1.0f / (float)BB);
}

extern "C" void kernel_launch(void* const* d_in, const int* in_sizes, int n_in,
                              void* d_out, int out_size, void* d_ws, size_t ws_size,
                              hipStream_t stream)
{
    const float* feats = (const float*)d_in[0];
    const int*   mask  = (const int*)d_in[1];
    const int*   tags  = (const int*)d_in[2];
    const float* trans = (const float*)d_in[3];
    float* out = (float*)d_out;
    float* ws  = (float*)d_ws;       // needs ~164 KB

    crf_scan<<<BB * 2, NTHR, 0, stream>>>(feats, mask, tags, trans, ws);
    crf_epi<<<1, 64, 0, stream>>>(ws, out);
}